// Round 1
// baseline (23963.684 us; speedup 1.0000x reference)
//
#include <hip/hip_runtime.h>

// LSTMForecast: B=256, T=512, IN=32, H=256, OUT=1, fp32.
// Round 0 design: batch-parallel persistent kernel, zero inter-block sync.
//   - pack_weights: transpose W into [k][gate] layout in d_ws (coalesced lane reads)
//   - lstm_forecast: 128 blocks x 512 threads; each block owns 2 batch rows.
//     Thread t: row = t>>8, j = t&255; computes gates i/f/g/o at column j for its row.
//     h kept in LDS, c in registers. 512 sequential steps, 2 layers, in-kernel.

#define TT 512
#define HH 256
#define BB 256
#define IN_DIM 32

// ws layout (floats)
constexpr int WT0_SZ = (IN_DIM + HH) * 1024;   // [288][1024] : k<32 -> W_ih0[g][k], else W_hh0[g][k-32]
constexpr int WT1_SZ = (HH + HH) * 1024;       // [512][1024] : k<256 -> W_ih1[g][k], else W_hh1[g][k-256]
constexpr int WT0_OFF = 0;
constexpr int WT1_OFF = WT0_OFF + WT0_SZ;
constexpr int B0_OFF  = WT1_OFF + WT1_SZ;
constexpr int B1_OFF  = B0_OFF + 1024;
constexpr int WS_FLOATS = B1_OFF + 1024;       // ~821k floats ~ 3.3 MB

__device__ __forceinline__ float sigmoidf_(float v) { return 1.0f / (1.0f + expf(-v)); }

__global__ void pack_weights(const float* __restrict__ Wih0, const float* __restrict__ Whh0,
                             const float* __restrict__ bih0, const float* __restrict__ bhh0,
                             const float* __restrict__ Wih1, const float* __restrict__ Whh1,
                             const float* __restrict__ bih1, const float* __restrict__ bhh1,
                             float* __restrict__ ws) {
  int idx = blockIdx.x * blockDim.x + threadIdx.x;
  if (idx < WT0_SZ) {
    int k = idx >> 10, g = idx & 1023;
    ws[WT0_OFF + idx] = (k < IN_DIM) ? Wih0[g * IN_DIM + k] : Whh0[g * HH + (k - IN_DIM)];
    return;
  }
  idx -= WT0_SZ;
  if (idx < WT1_SZ) {
    int k = idx >> 10, g = idx & 1023;
    ws[WT1_OFF + idx] = (k < HH) ? Wih1[g * HH + k] : Whh1[g * HH + (k - HH)];
    return;
  }
  idx -= WT1_SZ;
  if (idx < 1024) { ws[B0_OFF + idx] = bih0[idx] + bhh0[idx]; return; }
  idx -= 1024;
  if (idx < 1024) { ws[B1_OFF + idx] = bih1[idx] + bhh1[idx]; return; }
}

__global__ __launch_bounds__(512) void lstm_forecast(
    const float* __restrict__ x,      // [B][T][IN]
    const float* __restrict__ ws,
    const float* __restrict__ Wfc,    // [1][H]
    const float* __restrict__ bfc,    // [1]
    float* __restrict__ out) {        // [B][1]
  __shared__ float xs[2][IN_DIM];
  __shared__ float h0s[2][HH];
  __shared__ float h1s[2][HH];
  __shared__ float red[512];

  const int tid = threadIdx.x;
  const int row = tid >> 8;      // 0 or 1: which batch row of this block
  const int j   = tid & 255;     // hidden column

  const float* WT0 = ws + WT0_OFF;
  const float* WT1 = ws + WT1_OFF;
  const float* B0  = ws + B0_OFF;
  const float* B1  = ws + B1_OFF;

  // biases (resident in registers for the whole scan)
  const float bi0 = B0[j], bf0 = B0[j + 256], bg0 = B0[j + 512], bo0 = B0[j + 768];
  const float bi1 = B1[j], bf1 = B1[j + 256], bg1 = B1[j + 512], bo1 = B1[j + 768];

  h0s[row][j] = 0.0f;
  h1s[row][j] = 0.0f;
  float c0 = 0.0f, c1 = 0.0f;

  const long xbase0 = (long)(blockIdx.x * 2) * TT * IN_DIM;

  for (int t = 0; t < TT; ++t) {
    // stage x[b0..b1][t][0:32] into LDS
    if (tid < 64) {
      int r = tid >> 5, k = tid & 31;
      xs[r][k] = x[xbase0 + (long)r * TT * IN_DIM + t * IN_DIM + k];
    }
    __syncthreads();  // S1: xs ready; prev-iter h0s/h1s writes visible

    // ---- layer 0: gates = x_t @ Wih0^T + h0 @ Whh0^T + b ----
    float ai = bi0, af = bf0, ag = bg0, ao = bo0;
    {
      const float* w = WT0 + j;
      #pragma unroll 8
      for (int k = 0; k < IN_DIM; ++k) {
        float v = xs[row][k];
        ai = fmaf(v, w[0], ai);
        af = fmaf(v, w[256], af);
        ag = fmaf(v, w[512], ag);
        ao = fmaf(v, w[768], ao);
        w += 1024;
      }
      #pragma unroll 8
      for (int k = 0; k < HH; ++k) {
        float v = h0s[row][k];
        ai = fmaf(v, w[0], ai);
        af = fmaf(v, w[256], af);
        ag = fmaf(v, w[512], ag);
        ao = fmaf(v, w[768], ao);
        w += 1024;
      }
    }
    {
      float ii = sigmoidf_(ai);
      float ff = sigmoidf_(af);
      float gg = tanhf(ag);
      float oo = sigmoidf_(ao);
      c0 = ff * c0 + ii * gg;
      float h0n = oo * tanhf(c0);
      __syncthreads();            // S2: everyone done reading old h0s
      h0s[row][j] = h0n;
    }
    __syncthreads();              // S3: new h0s visible

    // ---- layer 1: gates = h0_new @ Wih1^T + h1 @ Whh1^T + b ----
    float a1i = bi1, a1f = bf1, a1g = bg1, a1o = bo1;
    {
      const float* w = WT1 + j;
      #pragma unroll 8
      for (int k = 0; k < HH; ++k) {
        float v = h0s[row][k];
        a1i = fmaf(v, w[0], a1i);
        a1f = fmaf(v, w[256], a1f);
        a1g = fmaf(v, w[512], a1g);
        a1o = fmaf(v, w[768], a1o);
        w += 1024;
      }
      #pragma unroll 8
      for (int k = 0; k < HH; ++k) {
        float v = h1s[row][k];
        a1i = fmaf(v, w[0], a1i);
        a1f = fmaf(v, w[256], a1f);
        a1g = fmaf(v, w[512], a1g);
        a1o = fmaf(v, w[768], a1o);
        w += 1024;
      }
    }
    {
      float ii = sigmoidf_(a1i);
      float ff = sigmoidf_(a1f);
      float gg = tanhf(a1g);
      float oo = sigmoidf_(a1o);
      c1 = ff * c1 + ii * gg;
      float h1n = oo * tanhf(c1);
      __syncthreads();            // S4: everyone done reading old h1s
      h1s[row][j] = h1n;
    }
    __syncthreads();              // S5: new h1s visible (also protects next-iter xs)
  }

  // ---- final FC: out[b] = h1 . Wfc + bfc ----
  red[tid] = h1s[row][j] * Wfc[j];
  __syncthreads();
  #pragma unroll
  for (int s = 128; s > 0; s >>= 1) {
    if (j < s) red[tid] += red[tid + s];
    __syncthreads();
  }
  if (j == 0) out[blockIdx.x * 2 + row] = red[row * 256] + bfc[0];
}

extern "C" void kernel_launch(void* const* d_in, const int* in_sizes, int n_in,
                              void* d_out, int out_size, void* d_ws, size_t ws_size,
                              hipStream_t stream) {
  const float* x    = (const float*)d_in[0];
  const float* Wih0 = (const float*)d_in[1];
  const float* Whh0 = (const float*)d_in[2];
  const float* bih0 = (const float*)d_in[3];
  const float* bhh0 = (const float*)d_in[4];
  const float* Wih1 = (const float*)d_in[5];
  const float* Whh1 = (const float*)d_in[6];
  const float* bih1 = (const float*)d_in[7];
  const float* bhh1 = (const float*)d_in[8];
  const float* Wfc  = (const float*)d_in[9];
  const float* bfc  = (const float*)d_in[10];
  float* out = (float*)d_out;
  float* ws  = (float*)d_ws;

  (void)in_sizes; (void)n_in; (void)out_size; (void)ws_size;

  // d_ws is re-poisoned before every launch: repack weights each call.
  int pack_threads = 256;
  int pack_blocks = (WS_FLOATS + pack_threads - 1) / pack_threads;
  pack_weights<<<pack_blocks, pack_threads, 0, stream>>>(
      Wih0, Whh0, bih0, bhh0, Wih1, Whh1, bih1, bhh1, ws);

  lstm_forecast<<<dim3(BB / 2), dim3(512), 0, stream>>>(x, ws, Wfc, bfc, out);
}